// Round 6
// baseline (97.220 us; speedup 1.0000x reference)
//
#include <hip/hip_runtime.h>

// CIN fully fused, d-contraction-first (R5 structure + deep prefetch):
//   out1[b,h] = sum_d h1[b,h,d];  h1 = sum_{f,q} W0[h,fq] x[b,f,d] x[b,q,d]
//   out2[b,h] = sum_p W1[h,p] U[b,p];  U[b,(f,q)] = sum_d x[b,f,d] h1[b,q,d]
// 256 blocks x 512 thr (G=8 batch/block, 1 block/CU, ~134KB LDS).
// R6 changes vs R5:
//   - phase 1: depth-2 register prefetch ring on wA1 (4 loads in flight)
//   - phase 3: depth-3 register prefetch ring on wA2 (12 loads in flight)
//     -> cover ~200-300cyc L2 latency at 2 waves/SIMD; K-loops become L2-BW-bound
//   - SROW 138 -> 136 so every short8 LDS access is 16B-aligned (b128)

#define F0   39
#define D_   16
#define H_   128
#define P0_  1521
#define P1_  4992
#define G8   8
#define NF1  (F0 * 2 * 8)   // 624 layer-1 A-frags
#define NF2  (F0 * 4 * 8)   // 1248 W1 A-frags
#define NC2  (F0 * 4)       // 156 out2 k-chunks
#define UBC  264            // Ub shorts per chunk (256 used + 8 pad), 528B: 16B-aligned
#define SROW 136            // S_bf row stride in shorts (272B = 17*16B: aligned)

typedef __attribute__((ext_vector_type(8))) short   short8;
typedef __attribute__((ext_vector_type(8))) __bf16  bf16x8;
typedef __attribute__((ext_vector_type(4))) float   floatx4;

__device__ __forceinline__ unsigned short bf16rne(float f) {
  unsigned int u = __float_as_uint(f);
  u += 0x7FFFu + ((u >> 16) & 1u);
  return (unsigned short)(u >> 16);
}

__device__ __forceinline__ floatx4 mfma16(short8 a, short8 b, floatx4 c) {
  return __builtin_amdgcn_mfma_f32_16x16x32_bf16(
      __builtin_bit_cast(bf16x8, a), __builtin_bit_cast(bf16x8, b), c, 0, 0, 0);
}

// ---------- pack W into MFMA A-frag order (verified R3-R5) ----------
__global__ __launch_bounds__(256) void pack_w_kernel(const float* __restrict__ w0,
                                                     const float* __restrict__ w1,
                                                     short8* __restrict__ wA1,
                                                     short8* __restrict__ wA2) {
  int id = blockIdx.x * 256 + threadIdx.x;
  union { short8 v; unsigned short e[8]; } pk;
  if (id < NF1 * 64) {
    int lane = id & 63, frag = id >> 6;
    int t = frag & 7, s = (frag >> 3) & 1, f = frag >> 4;
    int m = t * 16 + (lane & 15);
    int qb = s * 32 + (lane >> 4) * 8;
#pragma unroll
    for (int j = 0; j < 8; ++j) {
      int q = qb + j;
      float v = (q < F0) ? w0[(size_t)m * P0_ + f * F0 + q] : 0.f;
      pk.e[j] = bf16rne(v);
    }
    wA1[frag * 64 + lane] = pk.v;
  } else if (id < (NF1 + NF2) * 64) {
    int u = id - NF1 * 64;
    int lane = u & 63, frag = u >> 6;
    int t = frag & 7, s = (frag >> 3) & 3, f = frag >> 5;
    int m = t * 16 + (lane & 15);
    int pb = f * 128 + s * 32 + (lane >> 4) * 8;
#pragma unroll
    for (int j = 0; j < 8; ++j) pk.e[j] = bf16rne(w1[(size_t)m * P1_ + pb + j]);
    wA2[frag * 64 + lane] = pk.v;
  }
}

// ---------- fused main kernel ----------
__global__ __launch_bounds__(512, 2) void cin_fused(const float* __restrict__ x,
                                                    const short8* __restrict__ wA1,
                                                    const short8* __restrict__ wA2,
                                                    float* __restrict__ out) {
  // LDS map: [0,19968) xs fp32 | [19968, +34816) S_bf | then xTb/Ub (aliased)
  __shared__ __align__(16) char smem[19968 + 128 * SROW * 2 + NC2 * UBC * 2];
  float (*xs)[F0][D_]   = (float (*)[F0][D_])smem;
  unsigned short* S_bf  = (unsigned short*)(smem + 19968);            // [128][SROW]
  unsigned short* xTb   = (unsigned short*)(smem + 19968 + 128 * SROW * 2);
  unsigned short* Ub    = xTb;                                        // aliased (xTb dead first)

  const int tid  = threadIdx.x;
  const int lane = tid & 63;
  const int wv   = tid >> 6;      // 8 waves
  const int col  = lane & 15;
  const int quad = lane >> 4;
  const int b0   = blockIdx.x * G8;
  const floatx4 zf4 = {0.f, 0.f, 0.f, 0.f};

  // ---- stage x (coalesced float4) ----
  {
    const float4* xg = (const float4*)(x + (size_t)b0 * (F0 * D_));
    float4* xl = (float4*)smem;
    for (int i = tid; i < G8 * F0 * D_ / 4; i += 512) xl[i] = xg[i];
  }
  __syncthreads();

  // ---- xTb[g][q8][d][j] = bf16(x[g][q8*8+j][d]), zero-pad q>=39 ----
  for (int i = tid; i < G8 * 8 * D_; i += 512) {
    int d = i & 15, q8 = (i >> 4) & 7, g = i >> 7;
    union { short8 v; unsigned short e[8]; } pk;
#pragma unroll
    for (int j = 0; j < 8; ++j) {
      int q = q8 * 8 + j;
      pk.e[j] = (q < F0) ? bf16rne(xs[g][q][d]) : (unsigned short)0;
    }
    *(short8*)&xTb[(size_t)i * 8] = pk.v;
  }
  __syncthreads();

  // layer-1 B-frags (f-invariant), cached in VGPRs
  short8 bx[2][G8];
#pragma unroll
  for (int s = 0; s < 2; ++s)
#pragma unroll
    for (int g = 0; g < G8; ++g)
      bx[s][g] = *(const short8*)&xTb[(size_t)(((g * 8 + s * 4 + quad) * 16) + col) * 8];

  floatx4 acc2[G8];
#pragma unroll
  for (int g = 0; g < G8; ++g) acc2[g] = zf4;

  // ===== phase 1: layer 1 (wave = m-tile t = wv), depth-2 prefetch ring =====
  {
    const int t = wv;
    short8 pa[2][2];
#pragma unroll
    for (int s = 0; s < 2; ++s) {
      pa[0][s] = wA1[(size_t)((0 * 2 + s) * 8 + t) * 64 + lane];
      pa[1][s] = wA1[(size_t)((1 * 2 + s) * 8 + t) * 64 + lane];
    }
    for (int fb = 0; fb < F0 - 1; fb += 2) {
#pragma unroll
      for (int u = 0; u < 2; ++u) {
        const int f = fb + u;
        short8 a0 = pa[u][0], a1 = pa[u][1];
        int pf = (f + 2 <= F0 - 1) ? f + 2 : F0 - 1;
        pa[u][0] = wA1[(size_t)((pf * 2 + 0) * 8 + t) * 64 + lane];
        pa[u][1] = wA1[(size_t)((pf * 2 + 1) * 8 + t) * 64 + lane];
        float sx[G8];
#pragma unroll
        for (int g = 0; g < G8; ++g) sx[g] = xs[g][f][col];
#pragma unroll
        for (int g = 0; g < G8; ++g) {
          floatx4 acf = mfma16(a0, bx[0][g], zf4);
          acf = mfma16(a1, bx[1][g], acf);
#pragma unroll
          for (int r = 0; r < 4; ++r) acc2[g][r] += acf[r] * sx[g];
        }
      }
    }
    {  // tail f = 38 (consumes pa[0], loaded at f=36)
      const int f = F0 - 1;
      short8 a0 = pa[0][0], a1 = pa[0][1];
      float sx[G8];
#pragma unroll
      for (int g = 0; g < G8; ++g) sx[g] = xs[g][f][col];
#pragma unroll
      for (int g = 0; g < G8; ++g) {
        floatx4 acf = mfma16(a0, bx[0][g], zf4);
        acf = mfma16(a1, bx[1][g], acf);
#pragma unroll
        for (int r = 0; r < 4; ++r) acc2[g][r] += acf[r] * sx[g];
      }
    }
    // h1 -> S_bf (bf16). Row = h, col = g*16+d. (xTb dead after this barrier.)
#pragma unroll
    for (int g = 0; g < G8; ++g)
#pragma unroll
      for (int r = 0; r < 4; ++r)
        S_bf[(size_t)((t * 16 + quad * 4 + r) * SROW) + g * 16 + col] =
            bf16rne(acc2[g][r]);
  }
  __syncthreads();

  // ===== phase 2a: out1[b,h] = sum_d h1 (vector LDS reads, aligned) =====
  for (int i = tid; i < G8 * H_; i += 512) {
    int h = i & 127, g = i >> 7;
    union { short8 v; unsigned int u[4]; } w0v, w1v;
    w0v.v = *(const short8*)&S_bf[(size_t)h * SROW + g * 16];
    w1v.v = *(const short8*)&S_bf[(size_t)h * SROW + g * 16 + 8];
    float sum = 0.f;
#pragma unroll
    for (int p = 0; p < 4; ++p) {
      sum += __uint_as_float(w0v.u[p] << 16) + __uint_as_float(w0v.u[p] & 0xFFFF0000u);
      sum += __uint_as_float(w1v.u[p] << 16) + __uint_as_float(w1v.u[p] & 0xFFFF0000u);
    }
    out[(size_t)(b0 + g) * 256 + h] = sum;
  }

  // ===== phase 2b: U[g,(f,q)] = sum_d x[g,f,d] h1[g,q,d]  (wave = g = wv) =====
  // MFMA: A[m=f][k=d], B[n=q][k=d] -> C[m=f][n=q]; scatter to Ub in B-frag layout
  {
    const int g = wv;
    short8 af[3];
#pragma unroll
    for (int ft = 0; ft < 3; ++ft) {
      union { short8 v; unsigned short e[8]; } pk;
      int f = ft * 16 + col;
      if (quad < 2 && f < F0) {
        const float* xp = &xs[g][f][quad * 8];
#pragma unroll
        for (int j = 0; j < 8; ++j) pk.e[j] = bf16rne(xp[j]);
      } else {
#pragma unroll
        for (int j = 0; j < 8; ++j) pk.e[j] = 0;
      }
      af[ft] = pk.v;
    }
#pragma unroll
    for (int qt = 0; qt < 8; ++qt) {
      short8 bq;
      if (quad < 2) {
        bq = *(const short8*)&S_bf[(size_t)(qt * 16 + col) * SROW + g * 16 + quad * 8];
      } else {
        bq = short8{0, 0, 0, 0, 0, 0, 0, 0};
      }
#pragma unroll
      for (int ft = 0; ft < 3; ++ft) {
        floatx4 c2 = mfma16(af[ft], bq, zf4);
#pragma unroll
        for (int r = 0; r < 4; ++r) {
          int f = ft * 16 + quad * 4 + r;
          if (f < F0) {
            int c  = f * 4 + (qt >> 1);              // k-chunk = p/32
            int qb = (qt * 2 + (col >> 3)) & 3;      // (p%32)/8
            Ub[(size_t)c * UBC + qb * 64 + g * 8 + (col & 7)] = bf16rne(c2[r]);
          }
        }
      }
    }
  }
  __syncthreads();

  // ===== phase 3: out2 = sum_c W1frag(c) x Ufrag(c), depth-3 prefetch ring =====
  {
    const int t = wv;
    const short8 zero8 = {0, 0, 0, 0, 0, 0, 0, 0};
    floatx4 aco[4];
#pragma unroll
    for (int i = 0; i < 4; ++i) aco[i] = zf4;
    short8 pw[3][4];
#pragma unroll
    for (int slot = 0; slot < 3; ++slot)
#pragma unroll
      for (int i = 0; i < 4; ++i)
        pw[slot][i] = wA2[(size_t)((slot * 4 + i) * 8 + t) * 64 + lane];
    for (int cb3 = 0; cb3 < F0; cb3 += 3) {   // 39 = 3*13
#pragma unroll
      for (int u = 0; u < 3; ++u) {
        const int cb = cb3 + u;
        short8 cur[4];
#pragma unroll
        for (int i = 0; i < 4; ++i) cur[i] = pw[u][i];
        int pf = (cb + 3 <= F0 - 1) ? cb + 3 : cb;   // clamped reload, harmless
#pragma unroll
        for (int i = 0; i < 4; ++i)
          pw[u][i] = wA2[(size_t)((pf * 4 + i) * 8 + t) * 64 + lane];
#pragma unroll
        for (int i = 0; i < 4; ++i) {
          int c = cb * 4 + i;
          short8 bU = (col < 8)
              ? *(const short8*)&Ub[(size_t)c * UBC + quad * 64 + (col & 7) * 8]
              : zero8;
          aco[i] = mfma16(cur[i], bU, aco[i]);
        }
      }
    }
    if (col < 8) {
#pragma unroll
      for (int r = 0; r < 4; ++r) {
        float v = (aco[0][r] + aco[1][r]) + (aco[2][r] + aco[3][r]);
        out[(size_t)(b0 + col) * 256 + 128 + t * 16 + quad * 4 + r] = v;
      }
    }
  }
}

// ---------- fp32 last-resort fallback ----------
__global__ __launch_bounds__(128) void cin_fused_fallback(const float* __restrict__ x,
                                                          const float* __restrict__ w0,
                                                          const float* __restrict__ w1,
                                                          float* __restrict__ out) {
  __shared__ float4 xs4[F0 * D_ / 4];
  __shared__ float4 h1s4[H_ * D_ / 4];
  __shared__ float4 z4[H_ * D_ / 4];
  const int tid = threadIdx.x;
  const int b = blockIdx.x;
  const int hh = tid >> 2, dd = tid & 3, h0 = hh << 2;
  {
    const float4* xg = (const float4*)(x + (size_t)b * (F0 * D_));
    for (int i = tid; i < F0 * D_ / 4; i += 128) xs4[i] = xg[i];
  }
  __syncthreads();
  float acc[4][4];
#pragma unroll
  for (int i = 0; i < 4; ++i)
#pragma unroll
    for (int j = 0; j < 4; ++j) acc[i][j] = 0.f;
  for (int f = 0; f < F0; ++f) {
    for (int i = tid; i < F0 * D_ / 4; i += 128) {
      float4 xv = xs4[(f << 2) + (i & 3)], qv = xs4[i];
      z4[i] = make_float4(xv.x * qv.x, xv.y * qv.y, xv.z * qv.z, xv.w * qv.w);
    }
    __syncthreads();
    for (int q = 0; q < F0; ++q) {
      float4 zv = z4[(q << 2) + dd];
      int p = f * F0 + q;
      float ww[4] = {w0[(h0 + 0) * P0_ + p], w0[(h0 + 1) * P0_ + p],
                     w0[(h0 + 2) * P0_ + p], w0[(h0 + 3) * P0_ + p]};
      float zz[4] = {zv.x, zv.y, zv.z, zv.w};
#pragma unroll
      for (int hi = 0; hi < 4; ++hi)
#pragma unroll
        for (int di = 0; di < 4; ++di) acc[hi][di] += ww[hi] * zz[di];
    }
    __syncthreads();
  }
#pragma unroll
  for (int hi = 0; hi < 4; ++hi)
    h1s4[(h0 + hi) * 4 + dd] = make_float4(acc[hi][0], acc[hi][1], acc[hi][2], acc[hi][3]);
  __syncthreads();
  {
    float4 a0 = h1s4[tid * 4 + 0], a1 = h1s4[tid * 4 + 1];
    float4 a2 = h1s4[tid * 4 + 2], a3 = h1s4[tid * 4 + 3];
    out[(size_t)b * 256 + tid] = (a0.x + a0.y + a0.z + a0.w) + (a1.x + a1.y + a1.z + a1.w) +
                                 (a2.x + a2.y + a2.z + a2.w) + (a3.x + a3.y + a3.z + a3.w);
  }
#pragma unroll
  for (int i = 0; i < 4; ++i)
#pragma unroll
    for (int j = 0; j < 4; ++j) acc[i][j] = 0.f;
  for (int f = 0; f < F0; ++f) {
    for (int i = tid; i < H_ * D_ / 4; i += 128) {
      float4 xv = xs4[(f << 2) + (i & 3)], hv = h1s4[i];
      z4[i] = make_float4(xv.x * hv.x, xv.y * hv.y, xv.z * hv.z, xv.w * hv.w);
    }
    __syncthreads();
    for (int q = 0; q < H_; ++q) {
      float4 zv = z4[(q << 2) + dd];
      int p = f * H_ + q;
      float ww[4] = {w1[(h0 + 0) * P1_ + p], w1[(h0 + 1) * P1_ + p],
                     w1[(h0 + 2) * P1_ + p], w1[(h0 + 3) * P1_ + p]};
      float zz[4] = {zv.x, zv.y, zv.z, zv.w};
#pragma unroll
      for (int hi = 0; hi < 4; ++hi)
#pragma unroll
        for (int di = 0; di < 4; ++di) acc[hi][di] += ww[hi] * zz[di];
    }
    __syncthreads();
  }
#pragma unroll
  for (int hi = 0; hi < 4; ++hi)
    z4[(h0 + hi) * 4 + dd] = make_float4(acc[hi][0], acc[hi][1], acc[hi][2], acc[hi][3]);
  __syncthreads();
  {
    float4 a0 = z4[tid * 4 + 0], a1 = z4[tid * 4 + 1];
    float4 a2 = z4[tid * 4 + 2], a3 = z4[tid * 4 + 3];
    out[(size_t)b * 256 + 128 + tid] = (a0.x + a0.y + a0.z + a0.w) + (a1.x + a1.y + a1.z + a1.w) +
                                       (a2.x + a2.y + a2.z + a2.w) + (a3.x + a3.y + a3.z + a3.w);
  }
}

extern "C" void kernel_launch(void* const* d_in, const int* in_sizes, int n_in,
                              void* d_out, int out_size, void* d_ws, size_t ws_size,
                              hipStream_t stream) {
  const float* x  = (const float*)d_in[0];
  const float* w0 = (const float*)d_in[1];
  const float* w1 = (const float*)d_in[2];
  float* out = (float*)d_out;

  const size_t nfr    = (size_t)(NF1 + NF2) * 64;   // 119808 (frag,lane) pairs
  const size_t wbytes = nfr * sizeof(short8);       // ~1.92 MB

  if (ws_size >= wbytes) {
    short8* wA1 = (short8*)d_ws;
    short8* wA2 = wA1 + (size_t)NF1 * 64;
    pack_w_kernel<<<(int)((nfr + 255) / 256), 256, 0, stream>>>(w0, w1, wA1, wA2);
    cin_fused<<<256, 512, 0, stream>>>(x, wA1, wA2, out);
  } else {
    cin_fused_fallback<<<2048, 128, 0, stream>>>(x, w0, w1, out);
  }
}

// Round 7
// 96.150 us; speedup vs baseline: 1.0111x; 1.0111x over previous
//
#include <hip/hip_runtime.h>

// CIN fully fused, d-contraction-first. R7: 1024 thr/block = 16 waves = 4/SIMD.
//   out1[b,h] = sum_d h1[b,h,d];  h1 = sum_{f,q} W0[h,fq] x[b,f,d] x[b,q,d]
//   out2[b,h] = sum_p W1[h,p] U[b,p];  U[b,(f,q)] = sum_d x[b,f,d] h1[b,q,d]
// 256 blocks (G=8 batch/block, 1 block/CU, ~134KB LDS). Work split per phase:
//   phase 1: wave = (gh, t): m-tile t, batches gh*4..+3  (bx 32 VGPR, acc2 16)
//   phase 2b: wave = (g, qh): qt range qh*4..+4
//   phase 3: wave = (t, kh): k-half, reduced via 4.6KB fp32 LDS (stride 9)
// W frags still read exactly once per block -> L2 traffic unchanged.

#define F0   39
#define D_   16
#define H_   128
#define P0_  1521
#define P1_  4992
#define G8   8
#define NF1  (F0 * 2 * 8)   // 624 layer-1 A-frags
#define NF2  (F0 * 4 * 8)   // 1248 W1 A-frags
#define NC2  (F0 * 4)       // 156 out2 k-chunks
#define UBC  264            // Ub shorts per chunk (256 used + 8 pad)
#define SROW 136            // S_bf row stride in shorts (272B, 16B-aligned)

typedef __attribute__((ext_vector_type(8))) short   short8;
typedef __attribute__((ext_vector_type(8))) __bf16  bf16x8;
typedef __attribute__((ext_vector_type(4))) float   floatx4;

__device__ __forceinline__ unsigned short bf16rne(float f) {
  unsigned int u = __float_as_uint(f);
  u += 0x7FFFu + ((u >> 16) & 1u);
  return (unsigned short)(u >> 16);
}

__device__ __forceinline__ floatx4 mfma16(short8 a, short8 b, floatx4 c) {
  return __builtin_amdgcn_mfma_f32_16x16x32_bf16(
      __builtin_bit_cast(bf16x8, a), __builtin_bit_cast(bf16x8, b), c, 0, 0, 0);
}

// ---------- pack W into MFMA A-frag order (verified R3-R6) ----------
__global__ __launch_bounds__(256) void pack_w_kernel(const float* __restrict__ w0,
                                                     const float* __restrict__ w1,
                                                     short8* __restrict__ wA1,
                                                     short8* __restrict__ wA2) {
  int id = blockIdx.x * 256 + threadIdx.x;
  union { short8 v; unsigned short e[8]; } pk;
  if (id < NF1 * 64) {
    int lane = id & 63, frag = id >> 6;
    int t = frag & 7, s = (frag >> 3) & 1, f = frag >> 4;
    int m = t * 16 + (lane & 15);
    int qb = s * 32 + (lane >> 4) * 8;
#pragma unroll
    for (int j = 0; j < 8; ++j) {
      int q = qb + j;
      float v = (q < F0) ? w0[(size_t)m * P0_ + f * F0 + q] : 0.f;
      pk.e[j] = bf16rne(v);
    }
    wA1[frag * 64 + lane] = pk.v;
  } else if (id < (NF1 + NF2) * 64) {
    int u = id - NF1 * 64;
    int lane = u & 63, frag = u >> 6;
    int t = frag & 7, s = (frag >> 3) & 3, f = frag >> 5;
    int m = t * 16 + (lane & 15);
    int pb = f * 128 + s * 32 + (lane >> 4) * 8;
#pragma unroll
    for (int j = 0; j < 8; ++j) pk.e[j] = bf16rne(w1[(size_t)m * P1_ + pb + j]);
    wA2[frag * 64 + lane] = pk.v;
  }
}

// ---------- fused main kernel ----------
__global__ __launch_bounds__(1024, 4) void cin_fused(const float* __restrict__ x,
                                                     const short8* __restrict__ wA1,
                                                     const short8* __restrict__ wA2,
                                                     float* __restrict__ out) {
  // LDS map: [0,19968) xs fp32 (reused as S32 fp32 in phase 3)
  //          [19968, +34816) S_bf | then xTb/Ub (aliased)
  __shared__ __align__(16) char smem[19968 + 128 * SROW * 2 + NC2 * UBC * 2];
  float (*xs)[F0][D_]   = (float (*)[F0][D_])smem;
  float* S32            = (float*)smem;                               // phase 3 only
  unsigned short* S_bf  = (unsigned short*)(smem + 19968);            // [128][SROW]
  unsigned short* xTb   = (unsigned short*)(smem + 19968 + 128 * SROW * 2);
  unsigned short* Ub    = xTb;                                        // aliased

  const int tid  = threadIdx.x;
  const int lane = tid & 63;
  const int wv   = tid >> 6;      // 16 waves
  const int col  = lane & 15;
  const int quad = lane >> 4;
  const int b0   = blockIdx.x * G8;
  const floatx4 zf4 = {0.f, 0.f, 0.f, 0.f};

  // ---- stage x (coalesced float4) ----
  {
    const float4* xg = (const float4*)(x + (size_t)b0 * (F0 * D_));
    float4* xl = (float4*)smem;
    for (int i = tid; i < G8 * F0 * D_ / 4; i += 1024) xl[i] = xg[i];
  }
  __syncthreads();

  // ---- xTb[g][q8][d][j] = bf16(x[g][q8*8+j][d]), zero-pad q>=39 ----
  if (tid < G8 * 8 * D_) {
    int i = tid;
    int d = i & 15, q8 = (i >> 4) & 7, g = i >> 7;
    union { short8 v; unsigned short e[8]; } pk;
#pragma unroll
    for (int j = 0; j < 8; ++j) {
      int q = q8 * 8 + j;
      pk.e[j] = (q < F0) ? bf16rne(xs[g][q][d]) : (unsigned short)0;
    }
    *(short8*)&xTb[(size_t)i * 8] = pk.v;
  }
  __syncthreads();

  // ===== phase 1: wave = (gh, t); batches g0..g0+3, m-tile t =====
  {
    const int t  = wv & 7;
    const int g0 = (wv >> 3) * 4;

    short8 bx[2][4];
#pragma unroll
    for (int s = 0; s < 2; ++s)
#pragma unroll
      for (int gi = 0; gi < 4; ++gi)
        bx[s][gi] = *(const short8*)&xTb[(size_t)((((g0 + gi) * 8 + s * 4 + quad) * 16) + col) * 8];

    floatx4 acc2[4];
#pragma unroll
    for (int gi = 0; gi < 4; ++gi) acc2[gi] = zf4;

    short8 a0 = wA1[(size_t)(0 * 8 + t) * 64 + lane];
    short8 a1 = wA1[(size_t)(1 * 8 + t) * 64 + lane];
    for (int f = 0; f < F0; ++f) {
      int fn = (f + 1 < F0) ? f + 1 : f;
      short8 na0 = wA1[(size_t)((fn * 2 + 0) * 8 + t) * 64 + lane];
      short8 na1 = wA1[(size_t)((fn * 2 + 1) * 8 + t) * 64 + lane];
      float sx[4];
#pragma unroll
      for (int gi = 0; gi < 4; ++gi) sx[gi] = xs[g0 + gi][f][col];
#pragma unroll
      for (int gi = 0; gi < 4; ++gi) {
        floatx4 acf = mfma16(a0, bx[0][gi], zf4);
        acf = mfma16(a1, bx[1][gi], acf);
#pragma unroll
        for (int r = 0; r < 4; ++r) acc2[gi][r] += acf[r] * sx[gi];
      }
      a0 = na0; a1 = na1;
    }
    // h1 -> S_bf (bf16). Row = h, col = g*16+d. (two gh-waves: disjoint cols)
#pragma unroll
    for (int gi = 0; gi < 4; ++gi)
#pragma unroll
      for (int r = 0; r < 4; ++r)
        S_bf[(size_t)((t * 16 + quad * 4 + r) * SROW) + (g0 + gi) * 16 + col] =
            bf16rne(acc2[gi][r]);
  }
  __syncthreads();

  // ===== phase 2a: out1[b,h] = sum_d h1 (1024 threads, one shot) =====
  {
    int h = tid & 127, g = tid >> 7;
    union { short8 v; unsigned int u[4]; } w0v, w1v;
    w0v.v = *(const short8*)&S_bf[(size_t)h * SROW + g * 16];
    w1v.v = *(const short8*)&S_bf[(size_t)h * SROW + g * 16 + 8];
    float sum = 0.f;
#pragma unroll
    for (int p = 0; p < 4; ++p) {
      sum += __uint_as_float(w0v.u[p] << 16) + __uint_as_float(w0v.u[p] & 0xFFFF0000u);
      sum += __uint_as_float(w1v.u[p] << 16) + __uint_as_float(w1v.u[p] & 0xFFFF0000u);
    }
    out[(size_t)(b0 + g) * 256 + h] = sum;
  }

  // ===== phase 2b: wave = (g, qh). U[g,(f,q)] = sum_d x[g,f,d] h1[g,q,d] =====
  // MFMA: A[m=f][k=d], B[n=q][k=d] -> C[m=f][n=q]; scatter to Ub in B-frag layout
  {
    const int g  = wv & 7;
    const int qh = wv >> 3;
    short8 af[3];
#pragma unroll
    for (int ft = 0; ft < 3; ++ft) {
      union { short8 v; unsigned short e[8]; } pk;
      int f = ft * 16 + col;
      if (quad < 2 && f < F0) {
        const float* xp = &xs[g][f][quad * 8];
#pragma unroll
        for (int j = 0; j < 8; ++j) pk.e[j] = bf16rne(xp[j]);
      } else {
#pragma unroll
        for (int j = 0; j < 8; ++j) pk.e[j] = 0;
      }
      af[ft] = pk.v;
    }
#pragma unroll
    for (int qi = 0; qi < 4; ++qi) {
      const int qt = qh * 4 + qi;
      short8 bq;
      if (quad < 2) {
        bq = *(const short8*)&S_bf[(size_t)(qt * 16 + col) * SROW + g * 16 + quad * 8];
      } else {
        bq = short8{0, 0, 0, 0, 0, 0, 0, 0};
      }
#pragma unroll
      for (int ft = 0; ft < 3; ++ft) {
        floatx4 c2 = mfma16(af[ft], bq, zf4);
#pragma unroll
        for (int r = 0; r < 4; ++r) {
          int f = ft * 16 + quad * 4 + r;
          if (f < F0) {
            int c  = f * 4 + (qt >> 1);              // k-chunk = p/32
            int qb = (qt * 2 + (col >> 3)) & 3;      // (p%32)/8
            Ub[(size_t)c * UBC + qb * 64 + g * 8 + (col & 7)] = bf16rne(c2[r]);
          }
        }
      }
    }
  }
  __syncthreads();

  // ===== phase 3: wave = (t, kh). out2 = sum_c W1frag(c) x Ufrag(c) =====
  {
    const int t   = wv & 7;
    const int kh  = wv >> 3;
    const int cb0 = kh ? 20 : 0;
    const int cbN = kh ? F0 : 20;
    const short8 zero8 = {0, 0, 0, 0, 0, 0, 0, 0};
    floatx4 aco[4];
#pragma unroll
    for (int i = 0; i < 4; ++i) aco[i] = zf4;
    short8 aW[4];
#pragma unroll
    for (int i = 0; i < 4; ++i) aW[i] = wA2[(size_t)((cb0 * 4 + i) * 8 + t) * 64 + lane];
    for (int cb = cb0; cb < cbN; ++cb) {
      int cn = (cb + 1 < cbN) ? cb + 1 : cb;
      short8 nx[4];
#pragma unroll
      for (int i = 0; i < 4; ++i) nx[i] = wA2[(size_t)((cn * 4 + i) * 8 + t) * 64 + lane];
#pragma unroll
      for (int i = 0; i < 4; ++i) {
        int c = cb * 4 + i;
        short8 bU = (col < 8)
            ? *(const short8*)&Ub[(size_t)c * UBC + quad * 64 + (col & 7) * 8]
            : zero8;
        aco[i] = mfma16(aW[i], bU, aco[i]);
      }
#pragma unroll
      for (int i = 0; i < 4; ++i) aW[i] = nx[i];
    }
    float v[4];
#pragma unroll
    for (int r = 0; r < 4; ++r)
      v[r] = (aco[0][r] + aco[1][r]) + (aco[2][r] + aco[3][r]);

    // k-half reduction through S32 (xs region is dead; stride 9 -> <=2-way bank)
    if (kh == 0 && col < 8) {
#pragma unroll
      for (int r = 0; r < 4; ++r)
        S32[(size_t)(t * 16 + quad * 4 + r) * 9 + col] = v[r];
    }
    __syncthreads();
    if (kh == 1 && col < 8) {
#pragma unroll
      for (int r = 0; r < 4; ++r) {
        int h = t * 16 + quad * 4 + r;
        out[(size_t)(b0 + col) * 256 + 128 + h] = v[r] + S32[(size_t)h * 9 + col];
      }
    }
  }
}

// ---------- fp32 last-resort fallback ----------
__global__ __launch_bounds__(128) void cin_fused_fallback(const float* __restrict__ x,
                                                          const float* __restrict__ w0,
                                                          const float* __restrict__ w1,
                                                          float* __restrict__ out) {
  __shared__ float4 xs4[F0 * D_ / 4];
  __shared__ float4 h1s4[H_ * D_ / 4];
  __shared__ float4 z4[H_ * D_ / 4];
  const int tid = threadIdx.x;
  const int b = blockIdx.x;
  const int hh = tid >> 2, dd = tid & 3, h0 = hh << 2;
  {
    const float4* xg = (const float4*)(x + (size_t)b * (F0 * D_));
    for (int i = tid; i < F0 * D_ / 4; i += 128) xs4[i] = xg[i];
  }
  __syncthreads();
  float acc[4][4];
#pragma unroll
  for (int i = 0; i < 4; ++i)
#pragma unroll
    for (int j = 0; j < 4; ++j) acc[i][j] = 0.f;
  for (int f = 0; f < F0; ++f) {
    for (int i = tid; i < F0 * D_ / 4; i += 128) {
      float4 xv = xs4[(f << 2) + (i & 3)], qv = xs4[i];
      z4[i] = make_float4(xv.x * qv.x, xv.y * qv.y, xv.z * qv.z, xv.w * qv.w);
    }
    __syncthreads();
    for (int q = 0; q < F0; ++q) {
      float4 zv = z4[(q << 2) + dd];
      int p = f * F0 + q;
      float ww[4] = {w0[(h0 + 0) * P0_ + p], w0[(h0 + 1) * P0_ + p],
                     w0[(h0 + 2) * P0_ + p], w0[(h0 + 3) * P0_ + p]};
      float zz[4] = {zv.x, zv.y, zv.z, zv.w};
#pragma unroll
      for (int hi = 0; hi < 4; ++hi)
#pragma unroll
        for (int di = 0; di < 4; ++di) acc[hi][di] += ww[hi] * zz[di];
    }
    __syncthreads();
  }
#pragma unroll
  for (int hi = 0; hi < 4; ++hi)
    h1s4[(h0 + hi) * 4 + dd] = make_float4(acc[hi][0], acc[hi][1], acc[hi][2], acc[hi][3]);
  __syncthreads();
  {
    float4 a0 = h1s4[tid * 4 + 0], a1 = h1s4[tid * 4 + 1];
    float4 a2 = h1s4[tid * 4 + 2], a3 = h1s4[tid * 4 + 3];
    out[(size_t)b * 256 + tid] = (a0.x + a0.y + a0.z + a0.w) + (a1.x + a1.y + a1.z + a1.w) +
                                 (a2.x + a2.y + a2.z + a2.w) + (a3.x + a3.y + a3.z + a3.w);
  }
#pragma unroll
  for (int i = 0; i < 4; ++i)
#pragma unroll
    for (int j = 0; j < 4; ++j) acc[i][j] = 0.f;
  for (int f = 0; f < F0; ++f) {
    for (int i = tid; i < H_ * D_ / 4; i += 128) {
      float4 xv = xs4[(f << 2) + (i & 3)], hv = h1s4[i];
      z4[i] = make_float4(xv.x * hv.x, xv.y * hv.y, xv.z * hv.z, xv.w * hv.w);
    }
    __syncthreads();
    for (int q = 0; q < H_; ++q) {
      float4 zv = z4[(q << 2) + dd];
      int p = f * H_ + q;
      float ww[4] = {w1[(h0 + 0) * P1_ + p], w1[(h0 + 1) * P1_ + p],
                     w1[(h0 + 2) * P1_ + p], w1[(h0 + 3) * P1_ + p]};
      float zz[4] = {zv.x, zv.y, zv.z, zv.w};
#pragma unroll
      for (int hi = 0; hi < 4; ++hi)
#pragma unroll
        for (int di = 0; di < 4; ++di) acc[hi][di] += ww[hi] * zz[di];
    }
    __syncthreads();
  }
#pragma unroll
  for (int hi = 0; hi < 4; ++hi)
    z4[(h0 + hi) * 4 + dd] = make_float4(acc[hi][0], acc[hi][1], acc[hi][2], acc[hi][3]);
  __syncthreads();
  {
    float4 a0 = z4[tid * 4 + 0], a1 = z4[tid * 4 + 1];
    float4 a2 = z4[tid * 4 + 2], a3 = z4[tid * 4 + 3];
    out[(size_t)b * 256 + 128 + tid] = (a0.x + a0.y + a0.z + a0.w) + (a1.x + a1.y + a1.z + a1.w) +
                                       (a2.x + a2.y + a2.z + a2.w) + (a3.x + a3.y + a3.z + a3.w);
  }
}

extern "C" void kernel_launch(void* const* d_in, const int* in_sizes, int n_in,
                              void* d_out, int out_size, void* d_ws, size_t ws_size,
                              hipStream_t stream) {
  const float* x  = (const float*)d_in[0];
  const float* w0 = (const float*)d_in[1];
  const float* w1 = (const float*)d_in[2];
  float* out = (float*)d_out;

  const size_t nfr    = (size_t)(NF1 + NF2) * 64;   // 119808 (frag,lane) pairs
  const size_t wbytes = nfr * sizeof(short8);       // ~1.92 MB

  if (ws_size >= wbytes) {
    short8* wA1 = (short8*)d_ws;
    short8* wA2 = wA1 + (size_t)NF1 * 64;
    pack_w_kernel<<<(int)((nfr + 255) / 256), 256, 0, stream>>>(w0, w1, wA1, wA2);
    cin_fused<<<256, 1024, 0, stream>>>(x, wA1, wA2, out);
  } else {
    cin_fused_fallback<<<2048, 128, 0, stream>>>(x, w0, w1, out);
  }
}

// Round 8
// 94.187 us; speedup vs baseline: 1.0322x; 1.0208x over previous
//
#include <hip/hip_runtime.h>

// CIN fully fused, d-contraction-first. R8: Ub re-layout [f][g][q] to kill
// the 8-way bank conflicts + scatter VALU found in R7 counters.
//   out1[b,h] = sum_d h1[b,h,d];  h1 = sum_{f,q} W0[h,fq] x[b,f,d] x[b,q,d]
//   out2[b,h] = sum_p W1[h,p] U[b,p];  U[b,(f,q)] = sum_d x[b,f,d] h1[b,q,d]
// 256 blocks x 1024 thr (G=8 batch/block, 1 block/CU, ~140KB LDS).
//   phase 1: wave = (gh, t) as R7 (dup measured ~free R6 vs R7)
//   phase 2b: wave = (g, qh); writes Ub2[f][g][q], imm-offset b16 stores
//   phase 3: wave = (t, kh); B-frags = b128 from Ub2, 32-bank-clean

#define F0   39
#define D_   16
#define H_   128
#define P0_  1521
#define P1_  4992
#define G8   8
#define NF1  (F0 * 2 * 8)   // 624 layer-1 A-frags
#define NF2  (F0 * 4 * 8)   // 1248 W1 A-frags
#define SROW 136            // S_bf row stride in shorts (272B, 16B-aligned)
#define UGS  136            // Ub2 g-stride in shorts (272B: dw%32 = 4)
#define UFS  1096           // Ub2 f-stride in shorts (8*136+8; 2192B, 16B-aligned)

typedef __attribute__((ext_vector_type(8))) short   short8;
typedef __attribute__((ext_vector_type(8))) __bf16  bf16x8;
typedef __attribute__((ext_vector_type(4))) float   floatx4;

__device__ __forceinline__ unsigned short bf16rne(float f) {
  unsigned int u = __float_as_uint(f);
  u += 0x7FFFu + ((u >> 16) & 1u);
  return (unsigned short)(u >> 16);
}

__device__ __forceinline__ floatx4 mfma16(short8 a, short8 b, floatx4 c) {
  return __builtin_amdgcn_mfma_f32_16x16x32_bf16(
      __builtin_bit_cast(bf16x8, a), __builtin_bit_cast(bf16x8, b), c, 0, 0, 0);
}

// ---------- pack W into MFMA A-frag order (verified R3-R7) ----------
__global__ __launch_bounds__(256) void pack_w_kernel(const float* __restrict__ w0,
                                                     const float* __restrict__ w1,
                                                     short8* __restrict__ wA1,
                                                     short8* __restrict__ wA2) {
  int id = blockIdx.x * 256 + threadIdx.x;
  union { short8 v; unsigned short e[8]; } pk;
  if (id < NF1 * 64) {
    int lane = id & 63, frag = id >> 6;
    int t = frag & 7, s = (frag >> 3) & 1, f = frag >> 4;
    int m = t * 16 + (lane & 15);
    int qb = s * 32 + (lane >> 4) * 8;
#pragma unroll
    for (int j = 0; j < 8; ++j) {
      int q = qb + j;
      float v = (q < F0) ? w0[(size_t)m * P0_ + f * F0 + q] : 0.f;
      pk.e[j] = bf16rne(v);
    }
    wA1[frag * 64 + lane] = pk.v;
  } else if (id < (NF1 + NF2) * 64) {
    int u = id - NF1 * 64;
    int lane = u & 63, frag = u >> 6;
    int t = frag & 7, s = (frag >> 3) & 3, f = frag >> 5;
    int m = t * 16 + (lane & 15);
    int pb = f * 128 + s * 32 + (lane >> 4) * 8;
#pragma unroll
    for (int j = 0; j < 8; ++j) pk.e[j] = bf16rne(w1[(size_t)m * P1_ + pb + j]);
    wA2[frag * 64 + lane] = pk.v;
  }
}

// ---------- fused main kernel ----------
__global__ __launch_bounds__(1024, 4) void cin_fused(const float* __restrict__ x,
                                                     const short8* __restrict__ wA1,
                                                     const short8* __restrict__ wA2,
                                                     float* __restrict__ out) {
  // LDS: [0,19968) xs fp32 (reused as S32 in phase-3 reduce)
  //      [19968, +34816) S_bf | [54784, +85488) xTb then Ub2 (aliased)
  __shared__ __align__(16) char smem[19968 + 128 * SROW * 2 + F0 * UFS * 2];
  float (*xs)[F0][D_]   = (float (*)[F0][D_])smem;
  float* S32            = (float*)smem;                               // phase 3 only
  unsigned short* S_bf  = (unsigned short*)(smem + 19968);            // [128][SROW]
  unsigned short* xTb   = (unsigned short*)(smem + 19968 + 128 * SROW * 2);
  unsigned short* Ub2   = xTb;                                        // aliased

  const int tid  = threadIdx.x;
  const int lane = tid & 63;
  const int wv   = tid >> 6;      // 16 waves
  const int col  = lane & 15;
  const int quad = lane >> 4;
  const int b0   = blockIdx.x * G8;
  const floatx4 zf4 = {0.f, 0.f, 0.f, 0.f};

  // ---- stage x (coalesced float4) ----
  {
    const float4* xg = (const float4*)(x + (size_t)b0 * (F0 * D_));
    float4* xl = (float4*)smem;
    for (int i = tid; i < G8 * F0 * D_ / 4; i += 1024) xl[i] = xg[i];
  }
  __syncthreads();

  // ---- xTb[g][q8][d][j] = bf16(x[g][q8*8+j][d]), zero-pad q>=39 ----
  if (tid < G8 * 8 * D_) {
    int i = tid;
    int d = i & 15, q8 = (i >> 4) & 7, g = i >> 7;
    union { short8 v; unsigned short e[8]; } pk;
#pragma unroll
    for (int j = 0; j < 8; ++j) {
      int q = q8 * 8 + j;
      pk.e[j] = (q < F0) ? bf16rne(xs[g][q][d]) : (unsigned short)0;
    }
    *(short8*)&xTb[(size_t)i * 8] = pk.v;
  }
  __syncthreads();

  // ===== phase 1: wave = (gh, t); batches g0..g0+3, m-tile t =====
  {
    const int t  = wv & 7;
    const int g0 = (wv >> 3) * 4;

    short8 bx[2][4];
#pragma unroll
    for (int s = 0; s < 2; ++s)
#pragma unroll
      for (int gi = 0; gi < 4; ++gi)
        bx[s][gi] = *(const short8*)&xTb[(size_t)((((g0 + gi) * 8 + s * 4 + quad) * 16) + col) * 8];

    floatx4 acc2[4];
#pragma unroll
    for (int gi = 0; gi < 4; ++gi) acc2[gi] = zf4;

    short8 a0 = wA1[(size_t)(0 * 8 + t) * 64 + lane];
    short8 a1 = wA1[(size_t)(1 * 8 + t) * 64 + lane];
    for (int f = 0; f < F0; ++f) {
      int fn = (f + 1 < F0) ? f + 1 : f;
      short8 na0 = wA1[(size_t)((fn * 2 + 0) * 8 + t) * 64 + lane];
      short8 na1 = wA1[(size_t)((fn * 2 + 1) * 8 + t) * 64 + lane];
      float sx[4];
#pragma unroll
      for (int gi = 0; gi < 4; ++gi) sx[gi] = xs[g0 + gi][f][col];
#pragma unroll
      for (int gi = 0; gi < 4; ++gi) {
        floatx4 acf = mfma16(a0, bx[0][gi], zf4);
        acf = mfma16(a1, bx[1][gi], acf);
#pragma unroll
        for (int r = 0; r < 4; ++r) acc2[gi][r] += acf[r] * sx[gi];
      }
      a0 = na0; a1 = na1;
    }
    // h1 -> S_bf (bf16). Row = h, col = g*16+d.
#pragma unroll
    for (int gi = 0; gi < 4; ++gi)
#pragma unroll
      for (int r = 0; r < 4; ++r)
        S_bf[(size_t)((t * 16 + quad * 4 + r) * SROW) + (g0 + gi) * 16 + col] =
            bf16rne(acc2[gi][r]);
  }
  __syncthreads();

  // ===== phase 2a: out1[b,h] = sum_d h1 (1024 threads, one shot) =====
  {
    int h = tid & 127, g = tid >> 7;
    union { short8 v; unsigned int u[4]; } w0v, w1v;
    w0v.v = *(const short8*)&S_bf[(size_t)h * SROW + g * 16];
    w1v.v = *(const short8*)&S_bf[(size_t)h * SROW + g * 16 + 8];
    float sum = 0.f;
#pragma unroll
    for (int p = 0; p < 4; ++p) {
      sum += __uint_as_float(w0v.u[p] << 16) + __uint_as_float(w0v.u[p] & 0xFFFF0000u);
      sum += __uint_as_float(w1v.u[p] << 16) + __uint_as_float(w1v.u[p] & 0xFFFF0000u);
    }
    out[(size_t)(b0 + g) * 256 + h] = sum;
  }

  // ===== phase 2b: wave = (g, qh). U[g,(f,q)] = sum_d x[g,f,d] h1[g,q,d] =====
  // MFMA: A[m=f][k=d], B[n=q][k=d] -> C[m=f][n=q].
  // Store to Ub2[f][g][q]: imm-offset b16 stores, <=2-way banks.
  {
    const int g  = wv & 7;
    const int qh = wv >> 3;
    short8 af[3];
#pragma unroll
    for (int ft = 0; ft < 3; ++ft) {
      union { short8 v; unsigned short e[8]; } pk;
      int f = ft * 16 + col;
      if (quad < 2 && f < F0) {
        const float* xp = &xs[g][f][quad * 8];
#pragma unroll
        for (int j = 0; j < 8; ++j) pk.e[j] = bf16rne(xp[j]);
      } else {
#pragma unroll
        for (int j = 0; j < 8; ++j) pk.e[j] = 0;
      }
      af[ft] = pk.v;
    }
#pragma unroll
    for (int qi = 0; qi < 4; ++qi) {
      const int qt = qh * 4 + qi;
      short8 bq;
      if (quad < 2) {
        bq = *(const short8*)&S_bf[(size_t)(qt * 16 + col) * SROW + g * 16 + quad * 8];
      } else {
        bq = short8{0, 0, 0, 0, 0, 0, 0, 0};
      }
#pragma unroll
      for (int ft = 0; ft < 3; ++ft) {
        floatx4 c2 = mfma16(af[ft], bq, zf4);
        unsigned short* up =
            &Ub2[(size_t)(ft * 16 + quad * 4) * UFS + g * UGS + qt * 16 + col];
        if (ft < 2) {
#pragma unroll
          for (int r = 0; r < 4; ++r) up[r * UFS] = bf16rne(c2[r]);
        } else {
#pragma unroll
          for (int r = 0; r < 4; ++r)
            if (32 + quad * 4 + r < F0) up[r * UFS] = bf16rne(c2[r]);
        }
      }
    }
  }
  __syncthreads();

  // ===== phase 3: wave = (t, kh). out2 = sum_c W1frag(c) x Ufrag(c) =====
  // B-frag: k = quad*8+j over p = cb*128 + i*32 + k -> Ub2[cb][g=col][i*32+quad*8..+8]
  {
    const int t   = wv & 7;
    const int kh  = wv >> 3;
    const int cb0 = kh ? 20 : 0;
    const int cbN = kh ? F0 : 20;
    const short8 zero8 = {0, 0, 0, 0, 0, 0, 0, 0};
    floatx4 aco[4];
#pragma unroll
    for (int i = 0; i < 4; ++i) aco[i] = zf4;
    short8 aW[4];
#pragma unroll
    for (int i = 0; i < 4; ++i) aW[i] = wA2[(size_t)((cb0 * 4 + i) * 8 + t) * 64 + lane];
    for (int cb = cb0; cb < cbN; ++cb) {
      int cn = (cb + 1 < cbN) ? cb + 1 : cb;
      short8 nx[4];
#pragma unroll
      for (int i = 0; i < 4; ++i) nx[i] = wA2[(size_t)((cn * 4 + i) * 8 + t) * 64 + lane];
      const unsigned short* ubase = &Ub2[(size_t)cb * UFS + col * UGS + quad * 8];
#pragma unroll
      for (int i = 0; i < 4; ++i) {
        short8 bU = (col < 8) ? *(const short8*)(ubase + i * 32) : zero8;
        aco[i] = mfma16(aW[i], bU, aco[i]);
      }
#pragma unroll
      for (int i = 0; i < 4; ++i) aW[i] = nx[i];
    }
    float v[4];
#pragma unroll
    for (int r = 0; r < 4; ++r)
      v[r] = (aco[0][r] + aco[1][r]) + (aco[2][r] + aco[3][r]);

    // k-half reduction through S32 (xs dead; stride 9 -> <=2-way banks)
    if (kh == 0 && col < 8) {
#pragma unroll
      for (int r = 0; r < 4; ++r)
        S32[(size_t)(t * 16 + quad * 4 + r) * 9 + col] = v[r];
    }
    __syncthreads();
    if (kh == 1 && col < 8) {
#pragma unroll
      for (int r = 0; r < 4; ++r) {
        int h = t * 16 + quad * 4 + r;
        out[(size_t)(b0 + col) * 256 + 128 + h] = v[r] + S32[(size_t)h * 9 + col];
      }
    }
  }
}

// ---------- fp32 last-resort fallback ----------
__global__ __launch_bounds__(128) void cin_fused_fallback(const float* __restrict__ x,
                                                          const float* __restrict__ w0,
                                                          const float* __restrict__ w1,
                                                          float* __restrict__ out) {
  __shared__ float4 xs4[F0 * D_ / 4];
  __shared__ float4 h1s4[H_ * D_ / 4];
  __shared__ float4 z4[H_ * D_ / 4];
  const int tid = threadIdx.x;
  const int b = blockIdx.x;
  const int hh = tid >> 2, dd = tid & 3, h0 = hh << 2;
  {
    const float4* xg = (const float4*)(x + (size_t)b * (F0 * D_));
    for (int i = tid; i < F0 * D_ / 4; i += 128) xs4[i] = xg[i];
  }
  __syncthreads();
  float acc[4][4];
#pragma unroll
  for (int i = 0; i < 4; ++i)
#pragma unroll
    for (int j = 0; j < 4; ++j) acc[i][j] = 0.f;
  for (int f = 0; f < F0; ++f) {
    for (int i = tid; i < F0 * D_ / 4; i += 128) {
      float4 xv = xs4[(f << 2) + (i & 3)], qv = xs4[i];
      z4[i] = make_float4(xv.x * qv.x, xv.y * qv.y, xv.z * qv.z, xv.w * qv.w);
    }
    __syncthreads();
    for (int q = 0; q < F0; ++q) {
      float4 zv = z4[(q << 2) + dd];
      int p = f * F0 + q;
      float ww[4] = {w0[(h0 + 0) * P0_ + p], w0[(h0 + 1) * P0_ + p],
                     w0[(h0 + 2) * P0_ + p], w0[(h0 + 3) * P0_ + p]};
      float zz[4] = {zv.x, zv.y, zv.z, zv.w};
#pragma unroll
      for (int hi = 0; hi < 4; ++hi)
#pragma unroll
        for (int di = 0; di < 4; ++di) acc[hi][di] += ww[hi] * zz[di];
    }
    __syncthreads();
  }
#pragma unroll
  for (int hi = 0; hi < 4; ++hi)
    h1s4[(h0 + hi) * 4 + dd] = make_float4(acc[hi][0], acc[hi][1], acc[hi][2], acc[hi][3]);
  __syncthreads();
  {
    float4 a0 = h1s4[tid * 4 + 0], a1 = h1s4[tid * 4 + 1];
    float4 a2 = h1s4[tid * 4 + 2], a3 = h1s4[tid * 4 + 3];
    out[(size_t)b * 256 + tid] = (a0.x + a0.y + a0.z + a0.w) + (a1.x + a1.y + a1.z + a1.w) +
                                 (a2.x + a2.y + a2.z + a2.w) + (a3.x + a3.y + a3.z + a3.w);
  }
#pragma unroll
  for (int i = 0; i < 4; ++i)
#pragma unroll
    for (int j = 0; j < 4; ++j) acc[i][j] = 0.f;
  for (int f = 0; f < F0; ++f) {
    for (int i = tid; i < H_ * D_ / 4; i += 128) {
      float4 xv = xs4[(f << 2) + (i & 3)], hv = h1s4[i];
      z4[i] = make_float4(xv.x * hv.x, xv.y * hv.y, xv.z * hv.z, xv.w * hv.w);
    }
    __syncthreads();
    for (int q = 0; q < H_; ++q) {
      float4 zv = z4[(q << 2) + dd];
      int p = f * H_ + q;
      float ww[4] = {w1[(h0 + 0) * P1_ + p], w1[(h0 + 1) * P1_ + p],
                     w1[(h0 + 2) * P1_ + p], w1[(h0 + 3) * P1_ + p]};
      float zz[4] = {zv.x, zv.y, zv.z, zv.w};
#pragma unroll
      for (int hi = 0; hi < 4; ++hi)
#pragma unroll
        for (int di = 0; di < 4; ++di) acc[hi][di] += ww[hi] * zz[di];
    }
    __syncthreads();
  }
#pragma unroll
  for (int hi = 0; hi < 4; ++hi)
    z4[(h0 + hi) * 4 + dd] = make_float4(acc[hi][0], acc[hi][1], acc[hi][2], acc[hi][3]);
  __syncthreads();
  {
    float4 a0 = z4[tid * 4 + 0], a1 = z4[tid * 4 + 1];
    float4 a2 = z4[tid * 4 + 2], a3 = z4[tid * 4 + 3];
    out[(size_t)b * 256 + 128 + tid] = (a0.x + a0.y + a0.z + a0.w) + (a1.x + a1.y + a1.z + a1.w) +
                                       (a2.x + a2.y + a2.z + a2.w) + (a3.x + a3.y + a3.z + a3.w);
  }
}

extern "C" void kernel_launch(void* const* d_in, const int* in_sizes, int n_in,
                              void* d_out, int out_size, void* d_ws, size_t ws_size,
                              hipStream_t stream) {
  const float* x  = (const float*)d_in[0];
  const float* w0 = (const float*)d_in[1];
  const float* w1 = (const float*)d_in[2];
  float* out = (float*)d_out;

  const size_t nfr    = (size_t)(NF1 + NF2) * 64;   // 119808 (frag,lane) pairs
  const size_t wbytes = nfr * sizeof(short8);       // ~1.92 MB

  if (ws_size >= wbytes) {
    short8* wA1 = (short8*)d_ws;
    short8* wA2 = wA1 + (size_t)NF1 * 64;
    pack_w_kernel<<<(int)((nfr + 255) / 256), 256, 0, stream>>>(w0, w1, wA1, wA2);
    cin_fused<<<256, 1024, 0, stream>>>(x, wA1, wA2, out);
  } else {
    cin_fused_fallback<<<2048, 128, 0, stream>>>(x, w0, w1, out);
  }
}